// Round 8
// baseline (408.591 us; speedup 1.0000x reference)
//
#include <hip/hip_runtime.h>
#include <math.h>

// Problem constants
#define NB   4
#define SEQ  1024
#define DMOD 512
#define NHD  8
#define DK   64

typedef unsigned short ushort_t;
typedef __attribute__((ext_vector_type(8))) short bf16x8;
typedef __attribute__((ext_vector_type(4))) float f32x4;

// ---------------- workspace layout (bytes) ----------------
// wc 1KB | XQ 4M | XK 4M | XV 4M | WQ/WK/WV/WF 0.5M ea | QBF 4M | KBF 12M | VT 4M
// aliases: O2 (fp32 8M) over XQ+XK; OBF (bf16 4M) over XV — dead by then.
#define XQ_OFF   1024
#define XK_OFF   (XQ_OFF + 4194304)
#define XV_OFF   (XK_OFF + 4194304)
#define WQ_OFF   (XV_OFF + 4194304)
#define WK_OFF   (WQ_OFF + 524288)
#define WV_OFF   (WK_OFF + 524288)
#define WF_OFF   (WV_OFF + 524288)
#define QBF_OFF  (WF_OFF + 524288)
#define KBF_OFF  (QBF_OFF + 4194304)
#define VT_OFF   (KBF_OFF + 12582912)
#define O2_OFF   XQ_OFF
#define OBF_OFF  XV_OFF

__device__ inline ushort_t f2bf(float x) {
    unsigned u = __builtin_bit_cast(unsigned, x);
    unsigned r = (u + 0x7FFFu + ((u >> 16) & 1u)) >> 16;
    return (ushort_t)r;
}
__device__ inline unsigned pk2(float a, float b) {
    return (unsigned)f2bf(a) | ((unsigned)f2bf(b) << 16);
}

__global__ __launch_bounds__(64)
void prep_kernel(const float* __restrict__ rp_w1, const float* __restrict__ rp_b1,
                 const float* __restrict__ rp_w2, const float* __restrict__ rp_b2,
                 float* __restrict__ ws)
{
    int d = threadIdx.x;
    float w0 = 0.f, w1 = 0.f, cc = 0.f;
    for (int j = 0; j < 64; j++) {
        float r2 = rp_w2[d * 64 + j];
        w0 += r2 * rp_w1[j * 2 + 0];
        w1 += r2 * rp_w1[j * 2 + 1];
        cc += r2 * rp_b1[j];
    }
    ws[d] = cc + rp_b2[d];
    ws[64 + 2 * d + 0] = w0;
    ws[64 + 2 * d + 1] = w1;
}

__global__ __launch_bounds__(256)
void cvt3_kernel(const float* __restrict__ s0, const float* __restrict__ s1,
                 const float* __restrict__ s2, ushort_t* __restrict__ d0,
                 ushort_t* __restrict__ d1, ushort_t* __restrict__ d2)
{
    int t = blockIdx.x * 256 + threadIdx.x;
    const float* s = (blockIdx.y == 0) ? s0 : (blockIdx.y == 1) ? s1 : s2;
    ushort_t* d = (blockIdx.y == 0) ? d0 : (blockIdx.y == 1) ? d1 : d2;
    float4 v = *(const float4*)&s[t * 4];
    uint2 o = {pk2(v.x, v.y), pk2(v.z, v.w)};
    *(uint2*)&d[t * 4] = o;
}

__global__ __launch_bounds__(256)
void cvt4_kernel(const float* __restrict__ s0, const float* __restrict__ s1,
                 const float* __restrict__ s2, const float* __restrict__ s3,
                 ushort_t* __restrict__ d0, ushort_t* __restrict__ d1,
                 ushort_t* __restrict__ d2, ushort_t* __restrict__ d3)
{
    int t = blockIdx.x * 256 + threadIdx.x;
    const float* s = (blockIdx.y == 0) ? s0 : (blockIdx.y == 1) ? s1
                   : (blockIdx.y == 2) ? s2 : s3;
    ushort_t* d = (blockIdx.y == 0) ? d0 : (blockIdx.y == 1) ? d1
                : (blockIdx.y == 2) ? d2 : d3;
    float4 v = *(const float4*)&s[t * 4];
    uint2 o = {pk2(v.x, v.y), pk2(v.z, v.w)};
    *(uint2*)&d[t * 4] = o;
}

// MFMA NT GEMM: Y[n,o] = sum_m X[n,m]*Wt[o,m]; N=4096, O=512, M=512, bf16 in.
#define GP 72
template<int MODE>
__global__ __launch_bounds__(256)
void mfma_gemm(const ushort_t* __restrict__ X, const ushort_t* __restrict__ Wt,
               ushort_t* __restrict__ obf, float* __restrict__ ofp,
               const float* __restrict__ wc, const float* __restrict__ resid)
{
    __shared__ ushort_t Xs[64 * GP];
    __shared__ ushort_t Ws[64 * GP];
    const int n0 = blockIdx.y * 64;
    const int o0 = blockIdx.x * 64;
    const int tid = threadIdx.x;
    const int wave = tid >> 6, lane = tid & 63;
    const int m16 = lane & 15, g = lane >> 4;

    f32x4 acc[4] = {};
    for (int m0 = 0; m0 < 512; m0 += 64) {
        #pragma unroll
        for (int it = 0; it < 2; it++) {
            int idx = tid + it * 256;
            int row = idx >> 3, c8 = (idx & 7) * 8;
            *(uint4*)&Xs[row * GP + c8] = *(const uint4*)&X[(n0 + row) * 512 + m0 + c8];
            *(uint4*)&Ws[row * GP + c8] = *(const uint4*)&Wt[(o0 + row) * 512 + m0 + c8];
        }
        __syncthreads();
        #pragma unroll
        for (int kc = 0; kc < 2; kc++) {
            bf16x8 a = *(const bf16x8*)&Xs[(wave * 16 + m16) * GP + kc * 32 + g * 8];
            #pragma unroll
            for (int to = 0; to < 4; to++) {
                bf16x8 b = *(const bf16x8*)&Ws[(to * 16 + m16) * GP + kc * 32 + g * 8];
                acc[to] = __builtin_amdgcn_mfma_f32_16x16x32_bf16(a, b, acc[to], 0, 0, 0);
            }
        }
        __syncthreads();
    }
    #pragma unroll
    for (int to = 0; to < 4; to++) {
        int o = o0 + to * 16 + m16;
        #pragma unroll
        for (int r = 0; r < 4; r++) {
            int n = n0 + wave * 16 + g * 4 + r;
            float a = acc[to][r];
            int b = n >> 10, s = n & 1023, h = o >> 6, d = o & 63;
            if (MODE == 0) {
                obf[(((b * NHD + h) << 10) + s) * 64 + d] = f2bf(a);
            } else if (MODE == 1) {
                int base = ((((b * NHD + h) << 10) + s) * 192) + d;
                obf[base]       = f2bf(a * wc[d]);
                obf[base + 64]  = f2bf(a * wc[64 + 2 * d + 0]);
                obf[base + 128] = f2bf(a * wc[64 + 2 * d + 1]);
            } else if (MODE == 2) {
                obf[((b * NHD + h) * 64 + d) * 1024 + s] = f2bf(a);
            } else {
                ofp[n * 512 + o] = a + resid[n * 512 + o];
            }
        }
    }
}

// ---------------------------------------------------------------------------
// Fused score + softmax + PV, two-pass, no-max softmax (scores are O(1e-2)).
// LDS diet: Ks (27.7KB) + QP union buffer (9KB) = ~37KB -> 4 blocks/CU.
// Q fragments hoisted to regs; V B-fragments loaded direct from global (16B
// contiguous in Vt); P-tile write->read is within-wave (own 16-row strip), so
// pass 2 needs only 2 barriers per k-tile.
// ---------------------------------------------------------------------------
#define QPITCH 72
#define KPLANE (64 * QPITCH + 8)
#define SCL 0.18033688011f   // 0.125 * log2(e)
__global__ __launch_bounds__(256, 4)
void fused_attn(const ushort_t* __restrict__ Qbf, const ushort_t* __restrict__ Kbf,
                const float* __restrict__ pos, const ushort_t* __restrict__ Vt,
                float* __restrict__ attn, ushort_t* __restrict__ Obf)
{
    __shared__ ushort_t Ks[3 * KPLANE];
    __shared__ ushort_t QP[64 * QPITCH];   // Q tile, then reused as P tile
    const int bh = blockIdx.x;
    const int q0 = blockIdx.y * 64;
    const int tid = threadIdx.x;
    const int wave = tid >> 6, lane = tid & 63;
    const int m16 = lane & 15, g = lane >> 4;

    // stage Q tile, hoist A-fragments to registers
    #pragma unroll
    for (int it = 0; it < 2; it++) {
        int idx = tid + it * 256;
        int row = idx >> 3, c8 = (idx & 7) * 8;
        *(uint4*)&QP[row * QPITCH + c8] = *(const uint4*)&Qbf[((bh << 10) + q0 + row) * 64 + c8];
    }
    __syncthreads();
    bf16x8 aq0 = *(const bf16x8*)&QP[(wave * 16 + m16) * QPITCH + g * 8];
    bf16x8 aq1 = *(const bf16x8*)&QP[(wave * 16 + m16) * QPITCH + 32 + g * 8];
    __syncthreads();

    float lp[4] = {0.f, 0.f, 0.f, 0.f};

    // ---------------- pass 1: sum of exp2(s*SCL) ----------------
    for (int k0 = 0; k0 < 1024; k0 += 64) {
        #pragma unroll
        for (int it = 0; it < 6; it++) {
            int idx = tid + it * 256;
            int row = idx / 24, c = idx % 24;
            int j = c >> 3, d8 = (c & 7) * 8;
            *(uint4*)&Ks[j * KPLANE + row * QPITCH + d8] =
                *(const uint4*)&Kbf[((bh << 10) + k0 + row) * 192 + c * 8];
        }
        __syncthreads();

        f32x4 sc[4][3] = {};
        #pragma unroll
        for (int kc = 0; kc < 2; kc++) {
            bf16x8 af = kc ? aq1 : aq0;
            #pragma unroll
            for (int tk = 0; tk < 4; tk++)
                #pragma unroll
                for (int j = 0; j < 3; j++) {
                    bf16x8 bfv = *(const bf16x8*)&Ks[j * KPLANE + (tk * 16 + m16) * QPITCH + kc * 32 + g * 8];
                    sc[tk][j] = __builtin_amdgcn_mfma_f32_16x16x32_bf16(af, bfv, sc[tk][j], 0, 0, 0);
                }
        }

        #pragma unroll
        for (int r = 0; r < 4; r++) {
            int q = q0 + wave * 16 + g * 4 + r;
            float acc = 0.f;
            #pragma unroll
            for (int tk = 0; tk < 4; tk++) {
                float2 pp = *(const float2*)&pos[(q * 1024 + k0 + tk * 16 + m16) * 2];
                float s = (sc[tk][0][r] + pp.x * sc[tk][1][r] + pp.y * sc[tk][2][r]) * SCL;
                acc += __builtin_amdgcn_exp2f(s);
            }
            lp[r] += acc;
        }
        __syncthreads();
    }
    float inv_l[4];
    #pragma unroll
    for (int r = 0; r < 4; r++) {
        float s = lp[r];
        #pragma unroll
        for (int msk = 1; msk < 16; msk <<= 1) s += __shfl_xor(s, msk, 64);
        inv_l[r] = 1.0f / s;
    }

    // ---------------- pass 2: probs write + PV ----------------
    f32x4 ao[4] = {};
    for (int k0 = 0; k0 < 1024; k0 += 64) {
        #pragma unroll
        for (int it = 0; it < 6; it++) {
            int idx = tid + it * 256;
            int row = idx / 24, c = idx % 24;
            int j = c >> 3, d8 = (c & 7) * 8;
            *(uint4*)&Ks[j * KPLANE + row * QPITCH + d8] =
                *(const uint4*)&Kbf[((bh << 10) + k0 + row) * 192 + c * 8];
        }
        __syncthreads();

        // prefetch V B-fragments direct from global (16B contiguous each)
        bf16x8 vf[2][4];
        #pragma unroll
        for (int kc = 0; kc < 2; kc++)
            #pragma unroll
            for (int td = 0; td < 4; td++)
                vf[kc][td] = *(const bf16x8*)&Vt[(bh * 64 + td * 16 + m16) * 1024 + k0 + kc * 32 + g * 8];

        f32x4 sc[4][3] = {};
        #pragma unroll
        for (int kc = 0; kc < 2; kc++) {
            bf16x8 af = kc ? aq1 : aq0;
            #pragma unroll
            for (int tk = 0; tk < 4; tk++)
                #pragma unroll
                for (int j = 0; j < 3; j++) {
                    bf16x8 bfv = *(const bf16x8*)&Ks[j * KPLANE + (tk * 16 + m16) * QPITCH + kc * 32 + g * 8];
                    sc[tk][j] = __builtin_amdgcn_mfma_f32_16x16x32_bf16(af, bfv, sc[tk][j], 0, 0, 0);
                }
        }

        #pragma unroll
        for (int r = 0; r < 4; r++) {
            int q = q0 + wave * 16 + g * 4 + r;
            #pragma unroll
            for (int tk = 0; tk < 4; tk++) {
                float2 pp = *(const float2*)&pos[(q * 1024 + k0 + tk * 16 + m16) * 2];
                float s = (sc[tk][0][r] + pp.x * sc[tk][1][r] + pp.y * sc[tk][2][r]) * SCL;
                float p = __builtin_amdgcn_exp2f(s) * inv_l[r];
                attn[((bh << 10) + q) * 1024 + k0 + tk * 16 + m16] = p;
                QP[(wave * 16 + g * 4 + r) * QPITCH + tk * 16 + m16] = f2bf(p);
            }
        }
        // P strip is written and read by the same wave — no barrier needed.
        #pragma unroll
        for (int kc = 0; kc < 2; kc++) {
            bf16x8 a = *(const bf16x8*)&QP[(wave * 16 + m16) * QPITCH + kc * 32 + g * 8];
            #pragma unroll
            for (int td = 0; td < 4; td++)
                ao[td] = __builtin_amdgcn_mfma_f32_16x16x32_bf16(a, vf[kc][td], ao[td], 0, 0, 0);
        }
        __syncthreads();
    }

    const int b = bh >> 3, h = bh & 7;
    #pragma unroll
    for (int td = 0; td < 4; td++) {
        int d = td * 16 + m16;
        #pragma unroll
        for (int r = 0; r < 4; r++) {
            int q = q0 + wave * 16 + g * 4 + r;
            Obf[((b << 10) + q) * 512 + h * 64 + d] = f2bf(ao[td][r]);
        }
    }
}

__global__ __launch_bounds__(256)
void ln_kernel(const float* __restrict__ X, const float* __restrict__ g,
               const float* __restrict__ bta, float* __restrict__ out)
{
    const int row = blockIdx.x;
    const int tid = threadIdx.x;
    float2 x = *(const float2*)&X[row * 512 + tid * 2];
    float s  = x.x + x.y;
    float s2 = x.x * x.x + x.y * x.y;
    for (int off = 32; off; off >>= 1) {
        s  += __shfl_down(s, off, 64);
        s2 += __shfl_down(s2, off, 64);
    }
    __shared__ float rs[4], rs2[4];
    __shared__ float mu_s, rstd_s;
    int wave = tid >> 6, lane = tid & 63;
    if (lane == 0) { rs[wave] = s; rs2[wave] = s2; }
    __syncthreads();
    if (tid == 0) {
        float S1 = rs[0] + rs[1] + rs[2] + rs[3];
        float S2 = rs2[0] + rs2[1] + rs2[2] + rs2[3];
        float mu = S1 * (1.0f / 512.0f);
        float var = S2 * (1.0f / 512.0f) - mu * mu;
        mu_s = mu;
        rstd_s = rsqrtf(var + 1e-6f);
    }
    __syncthreads();
    float mu = mu_s, rstd = rstd_s;
    float2 gv = *(const float2*)&g[tid * 2];
    float2 bv = *(const float2*)&bta[tid * 2];
    float2 o;
    o.x = (x.x - mu) * rstd * gv.x + bv.x;
    o.y = (x.y - mu) * rstd * gv.y + bv.y;
    *(float2*)&out[row * 512 + tid * 2] = o;
}

extern "C" void kernel_launch(void* const* d_in, const int* in_sizes, int n_in,
                              void* d_out, int out_size, void* d_ws, size_t ws_size,
                              hipStream_t stream)
{
    const float* q       = (const float*)d_in[0];
    const float* k       = (const float*)d_in[1];
    const float* v       = (const float*)d_in[2];
    const float* pos_mat = (const float*)d_in[3];
    const float* w_qs    = (const float*)d_in[4];
    const float* w_ks    = (const float*)d_in[5];
    const float* w_vs    = (const float*)d_in[6];
    const float* w_fc    = (const float*)d_in[7];
    const float* rp_w1   = (const float*)d_in[8];
    const float* rp_b1   = (const float*)d_in[9];
    const float* rp_w2   = (const float*)d_in[10];
    const float* rp_b2   = (const float*)d_in[11];
    const float* ln_g    = (const float*)d_in[12];
    const float* ln_b    = (const float*)d_in[13];

    char* wsb = (char*)d_ws;
    float*    wc  = (float*)d_ws;
    ushort_t* XQ  = (ushort_t*)(wsb + XQ_OFF);
    ushort_t* XK  = (ushort_t*)(wsb + XK_OFF);
    ushort_t* XV  = (ushort_t*)(wsb + XV_OFF);
    ushort_t* WQ  = (ushort_t*)(wsb + WQ_OFF);
    ushort_t* WK  = (ushort_t*)(wsb + WK_OFF);
    ushort_t* WV  = (ushort_t*)(wsb + WV_OFF);
    ushort_t* WF  = (ushort_t*)(wsb + WF_OFF);
    ushort_t* Qbf = (ushort_t*)(wsb + QBF_OFF);
    ushort_t* Kbf = (ushort_t*)(wsb + KBF_OFF);
    ushort_t* Vt  = (ushort_t*)(wsb + VT_OFF);
    float*    O2  = (float*)(wsb + O2_OFF);
    ushort_t* Obf = (ushort_t*)(wsb + OBF_OFF);

    float* out  = (float*)d_out;       // final (B,S,512)
    float* attn = out + 2097152;       // (B,H,S,S) probs

    prep_kernel<<<dim3(1), dim3(64), 0, stream>>>(rp_w1, rp_b1, rp_w2, rp_b2, wc);

    cvt3_kernel<<<dim3(2048, 3), 256, 0, stream>>>(q, k, v, XQ, XK, XV);
    cvt4_kernel<<<dim3(256, 4), 256, 0, stream>>>(w_qs, w_ks, w_vs, w_fc, WQ, WK, WV, WF);

    dim3 gp(8, 64);
    mfma_gemm<0><<<gp, 256, 0, stream>>>(XQ, WQ, Qbf, nullptr, nullptr, nullptr);
    mfma_gemm<1><<<gp, 256, 0, stream>>>(XK, WK, Kbf, nullptr, wc, nullptr);
    mfma_gemm<2><<<gp, 256, 0, stream>>>(XV, WV, Vt, nullptr, nullptr, nullptr);

    fused_attn<<<dim3(32, 16), 256, 0, stream>>>(Qbf, Kbf, pos_mat, Vt, attn, Obf);

    mfma_gemm<3><<<gp, 256, 0, stream>>>(Obf, WF, nullptr, O2, nullptr, q);
    ln_kernel<<<dim3(4096), 256, 0, stream>>>(O2, ln_g, ln_b, out);
}